// Round 1
// baseline (692.204 us; speedup 1.0000x reference)
//
#include <hip/hip_runtime.h>
#include <stdint.h>

// Problem constants (fixed by reference)
#define NN 100000      // nodes
#define NE 1600000     // edges
#define K_DIM 128      // IN_DIM == HID_DIM
#define OUT_DIM 64

// ---------------------------------------------------------------------------
// CSR build: degree count -> exclusive scan -> bucket edges by dst
// ---------------------------------------------------------------------------

__global__ void deg_count_kernel(const int* __restrict__ ei, int* __restrict__ deg) {
    int e = blockIdx.x * blockDim.x + threadIdx.x;
    if (e < NE) {
        int d = ei[NE + e];            // dst row of edge_index
        atomicAdd(&deg[d], 1);
    }
}

__global__ void dis_kernel(const int* __restrict__ deg, float* __restrict__ dis) {
    int i = blockIdx.x * blockDim.x + threadIdx.x;
    if (i < NN) {
        int d = deg[i];
        dis[i] = (d > 0) ? rsqrtf((float)d) : 0.0f;
    }
}

// Per-block inclusive scan (1024 elems/block), writes exclusive part + block sum
__global__ void scan_block_kernel(const int* __restrict__ deg, int* __restrict__ excl,
                                  int* __restrict__ partial) {
    __shared__ int buf[1024];
    int tid = threadIdx.x;
    int i = blockIdx.x * 1024 + tid;
    int v = (i < NN) ? deg[i] : 0;
    buf[tid] = v;
    __syncthreads();
    for (int off = 1; off < 1024; off <<= 1) {
        int t = (tid >= off) ? buf[tid - off] : 0;
        __syncthreads();
        buf[tid] += t;
        __syncthreads();
    }
    if (i < NN) excl[i] = buf[tid] - v;      // exclusive within block
    if (tid == 1023) partial[blockIdx.x] = buf[1023];
}

// Exclusive scan of block partials (nb <= 128), single block of 128 threads
__global__ void scan_partials_kernel(int* __restrict__ partial, int nb) {
    __shared__ int buf[128];
    int tid = threadIdx.x;
    int v = (tid < nb) ? partial[tid] : 0;
    buf[tid] = v;
    __syncthreads();
    for (int off = 1; off < 128; off <<= 1) {
        int t = (tid >= off) ? buf[tid - off] : 0;
        __syncthreads();
        buf[tid] += t;
        __syncthreads();
    }
    if (tid < nb) partial[tid] = buf[tid] - v;   // exclusive
}

__global__ void scan_finalize_kernel(const int* __restrict__ excl, const int* __restrict__ partial,
                                     int* __restrict__ row_start, int* __restrict__ cursor) {
    int i = blockIdx.x * blockDim.x + threadIdx.x;
    if (i < NN) {
        int v = excl[i] + partial[i >> 10];
        row_start[i] = v;
        cursor[i] = v;
    }
    if (i == NN) row_start[NN] = NE;
}

__global__ void bucket_kernel(const int* __restrict__ ei, int* __restrict__ cursor,
                              int* __restrict__ ssrc) {
    int e = blockIdx.x * blockDim.x + threadIdx.x;
    if (e < NE) {
        int s = ei[e];
        int d = ei[NE + e];
        int pos = atomicAdd(&cursor[d], 1);
        ssrc[pos] = s;
    }
}

// ---------------------------------------------------------------------------
// Tiled f32 GEMM: out[M,N] = (A[M,128] @ W[128,N]) * dis[row]   (row-scaled)
// BM=64, BK=32. Block = 256 threads.
// ---------------------------------------------------------------------------
template <int N>
__global__ __launch_bounds__(256) void gemm_scaled_kernel(
        const float* __restrict__ A, const float* __restrict__ W,
        const float* __restrict__ dis, float* __restrict__ out, int M) {
    constexpr int BM = 64, BK = 32, K = K_DIM;
    constexpr int TN = 4;
    constexpr int TX = N / TN;        // 32 (N=128) or 16 (N=64)
    constexpr int TY = 256 / TX;      // 8 or 16
    constexpr int TM = BM / TY;       // 8 or 4

    __shared__ float As[BM][BK];
    __shared__ float Bs[BK][N];

    int tid = threadIdx.x;
    int tx = tid % TX, ty = tid / TX;
    int row0 = blockIdx.x * BM;

    float acc[TM][TN] = {};

    for (int k0 = 0; k0 < K; k0 += BK) {
        // Load A tile: 64x32 = 2048 floats; each thread: 2 x float4
        {
            int r = tid >> 3;           // 0..31
            int c = (tid & 7) * 4;      // 0,4,...,28
            float4 z = make_float4(0.f, 0.f, 0.f, 0.f);
            int ra = row0 + r;
            *(float4*)&As[r][c] = (ra < M) ? *(const float4*)&A[(size_t)ra * K + k0 + c] : z;
            int rb = row0 + r + 32;
            *(float4*)&As[r + 32][c] = (rb < M) ? *(const float4*)&A[(size_t)rb * K + k0 + c] : z;
        }
        // Load W tile: 32xN floats
        {
            constexpr int total = BK * N;
            #pragma unroll
            for (int base = 0; base < total; base += 1024) {
                int idx = base + tid * 4;
                if (idx < total) {
                    int r = idx / N, c = idx % N;
                    *(float4*)&Bs[r][c] = *(const float4*)&W[(size_t)(k0 + r) * N + c];
                }
            }
        }
        __syncthreads();
        #pragma unroll
        for (int kk = 0; kk < BK; kk++) {
            float a[TM], b[TN];
            #pragma unroll
            for (int i = 0; i < TM; i++) a[i] = As[ty * TM + i][kk];
            #pragma unroll
            for (int j = 0; j < TN; j++) b[j] = Bs[kk][tx * TN + j];
            #pragma unroll
            for (int i = 0; i < TM; i++)
                #pragma unroll
                for (int j = 0; j < TN; j++) acc[i][j] += a[i] * b[j];
        }
        __syncthreads();
    }

    #pragma unroll
    for (int i = 0; i < TM; i++) {
        int row = row0 + ty * TM + i;
        if (row < M) {
            float s = dis[row];
            float4 v = make_float4(acc[i][0] * s, acc[i][1] * s, acc[i][2] * s, acc[i][3] * s);
            *(float4*)&out[(size_t)row * N + tx * TN] = v;
        }
    }
}

// ---------------------------------------------------------------------------
// Aggregation: one wave (64 lanes) per node.
// out[d] = act( dis[d] * sum_{e in in(d)} g[ssrc[e]] + bias )
// F = feature dim (128: float2/lane, 64: float/lane)
// ---------------------------------------------------------------------------
template <int F, bool RELU>
__global__ __launch_bounds__(256) void agg_kernel(
        const float* __restrict__ g, const int* __restrict__ row_start,
        const int* __restrict__ ssrc, const float* __restrict__ dis,
        const float* __restrict__ bias, float* __restrict__ out) {
    int wave = (blockIdx.x * 256 + threadIdx.x) >> 6;
    int lane = threadIdx.x & 63;
    if (wave >= NN) return;

    int beg = row_start[wave];
    int end = row_start[wave + 1];
    float sc = dis[wave];

    if constexpr (F == 128) {
        float ax = 0.f, ay = 0.f;
        for (int e = beg; e < end; e++) {
            int s = ssrc[e];
            float2 v = *(const float2*)&g[(size_t)s * 128 + lane * 2];
            ax += v.x;
            ay += v.y;
        }
        float2 b = *(const float2*)&bias[lane * 2];
        float ox = sc * ax + b.x;
        float oy = sc * ay + b.y;
        if (RELU) { ox = fmaxf(ox, 0.f); oy = fmaxf(oy, 0.f); }
        *(float2*)&out[(size_t)wave * 128 + lane * 2] = make_float2(ox, oy);
    } else {
        float a = 0.f;
        for (int e = beg; e < end; e++) {
            int s = ssrc[e];
            a += g[(size_t)s * 64 + lane];
        }
        float o = sc * a + bias[lane];
        if (RELU) o = fmaxf(o, 0.f);
        out[(size_t)wave * 64 + lane] = o;
    }
}

// ---------------------------------------------------------------------------
// Launch
// ---------------------------------------------------------------------------
extern "C" void kernel_launch(void* const* d_in, const int* in_sizes, int n_in,
                              void* d_out, int out_size, void* d_ws, size_t ws_size,
                              hipStream_t stream) {
    const float* x  = (const float*)d_in[0];
    const int*   ei = (const int*)d_in[1];       // [2, NE] int32 per harness contract
    const float* W1 = (const float*)d_in[2];
    const float* b1 = (const float*)d_in[3];
    const float* W2 = (const float*)d_in[4];
    const float* b2 = (const float*)d_in[5];
    float* out = (float*)d_out;

    char* ws = (char*)d_ws;
    size_t off = 0;
    auto alloc = [&](size_t bytes) {
        void* p = ws + off;
        off = (off + bytes + 255) & ~(size_t)255;
        return p;
    };

    int*   deg_i     = (int*)alloc(NN * 4);
    float* dis       = (float*)alloc(NN * 4);
    int*   excl      = (int*)alloc(NN * 4);
    int*   partials  = (int*)alloc(128 * 4);
    int*   row_start = (int*)alloc((NN + 1) * 4);
    int*   cursor    = (int*)alloc(NN * 4);
    int*   ssrc      = (int*)alloc((size_t)NE * 4);
    float* g1        = (float*)alloc((size_t)NN * 128 * 4);  // reused as g2
    float* h         = (float*)alloc((size_t)NN * 128 * 4);
    float* g2        = g1;  // alias: g1 dead after agg1

    hipMemsetAsync(deg_i, 0, NN * 4, stream);

    const int TB = 256;
    deg_count_kernel<<<(NE + TB - 1) / TB, TB, 0, stream>>>(ei, deg_i);
    dis_kernel<<<(NN + TB - 1) / TB, TB, 0, stream>>>(deg_i, dis);

    const int NB_SCAN = (NN + 1023) / 1024;   // 98
    scan_block_kernel<<<NB_SCAN, 1024, 0, stream>>>(deg_i, excl, partials);
    scan_partials_kernel<<<1, 128, 0, stream>>>(partials, NB_SCAN);
    scan_finalize_kernel<<<(NN + 1 + TB - 1) / TB, TB, 0, stream>>>(excl, partials, row_start, cursor);

    bucket_kernel<<<(NE + TB - 1) / TB, TB, 0, stream>>>(ei, cursor, ssrc);

    const int GEMM_BLOCKS = (NN + 63) / 64;   // 1563
    gemm_scaled_kernel<128><<<GEMM_BLOCKS, 256, 0, stream>>>(x, W1, dis, g1, NN);

    const int AGG_BLOCKS = (NN + 3) / 4;      // 25000 (4 waves/block)
    agg_kernel<128, true><<<AGG_BLOCKS, 256, 0, stream>>>(g1, row_start, ssrc, dis, b1, h);

    gemm_scaled_kernel<64><<<GEMM_BLOCKS, 256, 0, stream>>>(h, W2, dis, g2, NN);

    agg_kernel<64, false><<<AGG_BLOCKS, 256, 0, stream>>>(g2, row_start, ssrc, dis, b2, out);
}

// Round 2
// 605.170 us; speedup vs baseline: 1.1438x; 1.1438x over previous
//
#include <hip/hip_runtime.h>
#include <stdint.h>

// Problem constants (fixed by reference)
#define NN 100000      // nodes
#define NE 1600000     // edges
#define K_DIM 128      // IN_DIM == HID_DIM

typedef unsigned int uint32;
typedef unsigned short ushort16;

__device__ __forceinline__ ushort16 f2bf(float f) {
    uint32 u = __float_as_uint(f);
    u += 0x7fffu + ((u >> 16) & 1u);   // round-to-nearest-even
    return (ushort16)(u >> 16);
}
__device__ __forceinline__ float bf_lo(uint32 u) { return __uint_as_float(u << 16); }
__device__ __forceinline__ float bf_hi(uint32 u) { return __uint_as_float(u & 0xffff0000u); }

// ---------------------------------------------------------------------------
// CSR build: degree count -> exclusive scan -> bucket edges by dst
// ---------------------------------------------------------------------------

__global__ void deg_count_kernel(const int* __restrict__ ei, int* __restrict__ deg) {
    int e = blockIdx.x * blockDim.x + threadIdx.x;
    if (e < NE) {
        int d = ei[NE + e];            // dst row of edge_index
        atomicAdd(&deg[d], 1);
    }
}

__global__ void dis_kernel(const int* __restrict__ deg, float* __restrict__ dis) {
    int i = blockIdx.x * blockDim.x + threadIdx.x;
    if (i < NN) {
        int d = deg[i];
        dis[i] = (d > 0) ? rsqrtf((float)d) : 0.0f;
    }
}

__global__ void scan_block_kernel(const int* __restrict__ deg, int* __restrict__ excl,
                                  int* __restrict__ partial) {
    __shared__ int buf[1024];
    int tid = threadIdx.x;
    int i = blockIdx.x * 1024 + tid;
    int v = (i < NN) ? deg[i] : 0;
    buf[tid] = v;
    __syncthreads();
    for (int off = 1; off < 1024; off <<= 1) {
        int t = (tid >= off) ? buf[tid - off] : 0;
        __syncthreads();
        buf[tid] += t;
        __syncthreads();
    }
    if (i < NN) excl[i] = buf[tid] - v;
    if (tid == 1023) partial[blockIdx.x] = buf[1023];
}

__global__ void scan_partials_kernel(int* __restrict__ partial, int nb) {
    __shared__ int buf[128];
    int tid = threadIdx.x;
    int v = (tid < nb) ? partial[tid] : 0;
    buf[tid] = v;
    __syncthreads();
    for (int off = 1; off < 128; off <<= 1) {
        int t = (tid >= off) ? buf[tid - off] : 0;
        __syncthreads();
        buf[tid] += t;
        __syncthreads();
    }
    if (tid < nb) partial[tid] = buf[tid] - v;
}

__global__ void scan_finalize_kernel(const int* __restrict__ excl, const int* __restrict__ partial,
                                     int* __restrict__ row_start, int* __restrict__ cursor) {
    int i = blockIdx.x * blockDim.x + threadIdx.x;
    if (i < NN) {
        int v = excl[i] + partial[i >> 10];
        row_start[i] = v;
        cursor[i] = v;
    }
    if (i == NN) row_start[NN] = NE;
}

__global__ void bucket_kernel(const int* __restrict__ ei, int* __restrict__ cursor,
                              int* __restrict__ ssrc) {
    int e = blockIdx.x * blockDim.x + threadIdx.x;
    if (e < NE) {
        int s = ei[e];
        int d = ei[NE + e];
        int pos = atomicAdd(&cursor[d], 1);
        ssrc[pos] = s;
    }
}

// ---------------------------------------------------------------------------
// Tiled f32 GEMM, bf16 output: out[M,N] = bf16( (A[M,128] @ W[128,N]) * dis[row] )
// BM=64, BK=32, A-tile transposed in LDS for vectorized fragment reads.
// ---------------------------------------------------------------------------
template <int N>
__global__ __launch_bounds__(256) void gemm_scaled_kernel(
        const float* __restrict__ A, const float* __restrict__ W,
        const float* __restrict__ dis, ushort16* __restrict__ out, int M) {
    constexpr int BM = 64, BK = 32, K = K_DIM;
    constexpr int TN = 4;
    constexpr int TX = N / TN;        // 32 (N=128) or 16 (N=64)
    constexpr int TY = 256 / TX;      // 8 or 16
    constexpr int TM = BM / TY;       // 8 or 4
    constexpr int AP = BM + 4;        // pad: keeps rows 16B-aligned (272B stride)

    __shared__ float As[BK][AP];      // transposed: As[k][m]
    __shared__ float Bs[BK][N];

    int tid = threadIdx.x;
    int tx = tid % TX, ty = tid / TX;
    int row0 = blockIdx.x * BM;

    float acc[TM][TN] = {};

    for (int k0 = 0; k0 < K; k0 += BK) {
        // Load A tile (64x32 floats) transposed into LDS
        {
            int r = tid >> 3;           // 0..31
            int c = (tid & 7) * 4;      // 0,4,...,28
            float4 z = make_float4(0.f, 0.f, 0.f, 0.f);
            int ra = row0 + r;
            float4 va = (ra < M) ? *(const float4*)&A[(size_t)ra * K + k0 + c] : z;
            int rb = row0 + r + 32;
            float4 vb = (rb < M) ? *(const float4*)&A[(size_t)rb * K + k0 + c] : z;
            As[c + 0][r] = va.x; As[c + 1][r] = va.y; As[c + 2][r] = va.z; As[c + 3][r] = va.w;
            As[c + 0][r + 32] = vb.x; As[c + 1][r + 32] = vb.y;
            As[c + 2][r + 32] = vb.z; As[c + 3][r + 32] = vb.w;
        }
        // Load W tile: 32xN floats
        {
            constexpr int total = BK * N;
            #pragma unroll
            for (int base = 0; base < total; base += 1024) {
                int idx = base + tid * 4;
                if (idx < total) {
                    int r = idx / N, c = idx % N;
                    *(float4*)&Bs[r][c] = *(const float4*)&W[(size_t)(k0 + r) * N + c];
                }
            }
        }
        __syncthreads();
        #pragma unroll
        for (int kk = 0; kk < BK; kk++) {
            float a[TM], b[TN];
            #pragma unroll
            for (int i = 0; i < TM; i += 4)
                *(float4*)&a[i] = *(const float4*)&As[kk][ty * TM + i];
            *(float4*)&b[0] = *(const float4*)&Bs[kk][tx * TN];
            #pragma unroll
            for (int i = 0; i < TM; i++)
                #pragma unroll
                for (int j = 0; j < TN; j++) acc[i][j] += a[i] * b[j];
        }
        __syncthreads();
    }

    #pragma unroll
    for (int i = 0; i < TM; i++) {
        int row = row0 + ty * TM + i;
        if (row < M) {
            float s = dis[row];
            ushort4 v;
            v.x = f2bf(acc[i][0] * s); v.y = f2bf(acc[i][1] * s);
            v.z = f2bf(acc[i][2] * s); v.w = f2bf(acc[i][3] * s);
            *(ushort4*)&out[(size_t)row * N + tx * TN] = v;
        }
    }
}

// ---------------------------------------------------------------------------
// Aggregation layer 1: F=128, bf16 gather -> f32 out with ReLU.
// One wave per node; lane loads a bf16 pair (4B) -> 256B/row transactions.
// out[d] = relu( dis[d] * sum_{e in in(d)} g[ssrc[e]] + bias )
// ---------------------------------------------------------------------------
__global__ __launch_bounds__(256) void agg128_kernel(
        const ushort16* __restrict__ g, const int* __restrict__ row_start,
        const int* __restrict__ ssrc, const float* __restrict__ dis,
        const float* __restrict__ bias, float* __restrict__ out) {
    int wave = (blockIdx.x * 256 + threadIdx.x) >> 6;
    int lane = threadIdx.x & 63;
    if (wave >= NN) return;

    int beg = row_start[wave];
    int end = row_start[wave + 1];
    float sc = dis[wave];

    float ax = 0.f, ay = 0.f;
    for (int e = beg; e < end; e++) {
        int s = ssrc[e];
        uint32 u = *(const uint32*)&g[(size_t)s * 128 + lane * 2];
        ax += bf_lo(u);
        ay += bf_hi(u);
    }
    float2 b = *(const float2*)&bias[lane * 2];
    float ox = fmaxf(sc * ax + b.x, 0.f);
    float oy = fmaxf(sc * ay + b.y, 0.f);
    *(float2*)&out[(size_t)wave * 128 + lane * 2] = make_float2(ox, oy);
}

// ---------------------------------------------------------------------------
// Aggregation layer 2: F=64, bf16 gather -> f32 out (no activation).
// One wave per node; lane-halves process two edges in parallel (4B/lane),
// combined via shfl_xor(32). Lanes 0..31 store float2 (256B/row).
// ---------------------------------------------------------------------------
__global__ __launch_bounds__(256) void agg64_kernel(
        const ushort16* __restrict__ g, const int* __restrict__ row_start,
        const int* __restrict__ ssrc, const float* __restrict__ dis,
        const float* __restrict__ bias, float* __restrict__ out) {
    int wave = (blockIdx.x * 256 + threadIdx.x) >> 6;
    int lane = threadIdx.x & 63;
    if (wave >= NN) return;

    int beg = row_start[wave];
    int end = row_start[wave + 1];
    float sc = dis[wave];
    int half = lane >> 5;       // which edge of the pair
    int l2 = lane & 31;         // feature pair index

    float ax = 0.f, ay = 0.f;
    for (int e = beg + half; e < end; e += 2) {
        int s = ssrc[e];
        uint32 u = *(const uint32*)&g[(size_t)s * 64 + l2 * 2];
        ax += bf_lo(u);
        ay += bf_hi(u);
    }
    ax += __shfl_xor(ax, 32);
    ay += __shfl_xor(ay, 32);
    if (half == 0) {
        float2 b = *(const float2*)&bias[l2 * 2];
        *(float2*)&out[(size_t)wave * 64 + l2 * 2] =
            make_float2(sc * ax + b.x, sc * ay + b.y);
    }
}

// ---------------------------------------------------------------------------
// Launch
// ---------------------------------------------------------------------------
extern "C" void kernel_launch(void* const* d_in, const int* in_sizes, int n_in,
                              void* d_out, int out_size, void* d_ws, size_t ws_size,
                              hipStream_t stream) {
    const float* x  = (const float*)d_in[0];
    const int*   ei = (const int*)d_in[1];       // [2, NE] int32 per harness contract
    const float* W1 = (const float*)d_in[2];
    const float* b1 = (const float*)d_in[3];
    const float* W2 = (const float*)d_in[4];
    const float* b2 = (const float*)d_in[5];
    float* out = (float*)d_out;

    char* ws = (char*)d_ws;
    size_t off = 0;
    auto alloc = [&](size_t bytes) {
        void* p = ws + off;
        off = (off + bytes + 255) & ~(size_t)255;
        return p;
    };

    int*      deg_i     = (int*)alloc(NN * 4);
    float*    dis       = (float*)alloc(NN * 4);
    int*      excl      = (int*)alloc(NN * 4);
    int*      partials  = (int*)alloc(128 * 4);
    int*      row_start = (int*)alloc((NN + 1) * 4);
    int*      cursor    = (int*)alloc(NN * 4);
    int*      ssrc      = (int*)alloc((size_t)NE * 4);
    ushort16* g1        = (ushort16*)alloc((size_t)NN * 128 * 2);  // bf16, reused as g2
    float*    h         = (float*)alloc((size_t)NN * 128 * 4);     // f32 hidden
    ushort16* g2        = g1;  // alias: g1 dead after agg1 (g2 needs half the bytes)

    hipMemsetAsync(deg_i, 0, NN * 4, stream);

    const int TB = 256;
    deg_count_kernel<<<(NE + TB - 1) / TB, TB, 0, stream>>>(ei, deg_i);
    dis_kernel<<<(NN + TB - 1) / TB, TB, 0, stream>>>(deg_i, dis);

    const int NB_SCAN = (NN + 1023) / 1024;   // 98
    scan_block_kernel<<<NB_SCAN, 1024, 0, stream>>>(deg_i, excl, partials);
    scan_partials_kernel<<<1, 128, 0, stream>>>(partials, NB_SCAN);
    scan_finalize_kernel<<<(NN + 1 + TB - 1) / TB, TB, 0, stream>>>(excl, partials, row_start, cursor);

    bucket_kernel<<<(NE + TB - 1) / TB, TB, 0, stream>>>(ei, cursor, ssrc);

    const int GEMM_BLOCKS = (NN + 63) / 64;   // 1563
    gemm_scaled_kernel<128><<<GEMM_BLOCKS, 256, 0, stream>>>(x, W1, dis, g1, NN);

    const int AGG_BLOCKS = (NN + 3) / 4;      // 25000 (4 waves/block)
    agg128_kernel<<<AGG_BLOCKS, 256, 0, stream>>>(g1, row_start, ssrc, dis, b1, h);

    gemm_scaled_kernel<64><<<GEMM_BLOCKS, 256, 0, stream>>>(h, W2, dis, g2, NN);

    agg64_kernel<<<AGG_BLOCKS, 256, 0, stream>>>(g2, row_start, ssrc, dis, b2, out);
}

// Round 3
// 485.975 us; speedup vs baseline: 1.4244x; 1.2453x over previous
//
#include <hip/hip_runtime.h>
#include <stdint.h>

// Problem constants (fixed by reference)
#define NN 100000      // nodes
#define NE 1600000     // edges
#define K_DIM 128      // IN_DIM == HID_DIM

typedef unsigned int uint32;
typedef unsigned short ushort16;

__device__ __forceinline__ ushort16 f2bf(float f) {
    uint32 u = __float_as_uint(f);
    u += 0x7fffu + ((u >> 16) & 1u);   // round-to-nearest-even
    return (ushort16)(u >> 16);
}
__device__ __forceinline__ float bf_lo(uint32 u) { return __uint_as_float(u << 16); }
__device__ __forceinline__ float bf_hi(uint32 u) { return __uint_as_float(u & 0xffff0000u); }

// ---------------------------------------------------------------------------
// CSR build: degree count -> exclusive scan -> bucket edges by dst
// ---------------------------------------------------------------------------

__global__ void deg_count_kernel(const int* __restrict__ ei, int* __restrict__ deg) {
    int e = blockIdx.x * blockDim.x + threadIdx.x;
    if (e < NE) {
        int d = ei[NE + e];
        atomicAdd(&deg[d], 1);
    }
}

__global__ void dis_kernel(const int* __restrict__ deg, float* __restrict__ dis) {
    int i = blockIdx.x * blockDim.x + threadIdx.x;
    if (i < NN) {
        int d = deg[i];
        dis[i] = (d > 0) ? rsqrtf((float)d) : 0.0f;
    }
}

__global__ void scan_block_kernel(const int* __restrict__ deg, int* __restrict__ excl,
                                  int* __restrict__ partial) {
    __shared__ int buf[1024];
    int tid = threadIdx.x;
    int i = blockIdx.x * 1024 + tid;
    int v = (i < NN) ? deg[i] : 0;
    buf[tid] = v;
    __syncthreads();
    for (int off = 1; off < 1024; off <<= 1) {
        int t = (tid >= off) ? buf[tid - off] : 0;
        __syncthreads();
        buf[tid] += t;
        __syncthreads();
    }
    if (i < NN) excl[i] = buf[tid] - v;
    if (tid == 1023) partial[blockIdx.x] = buf[1023];
}

__global__ void scan_partials_kernel(int* __restrict__ partial, int nb) {
    __shared__ int buf[128];
    int tid = threadIdx.x;
    int v = (tid < nb) ? partial[tid] : 0;
    buf[tid] = v;
    __syncthreads();
    for (int off = 1; off < 128; off <<= 1) {
        int t = (tid >= off) ? buf[tid - off] : 0;
        __syncthreads();
        buf[tid] += t;
        __syncthreads();
    }
    if (tid < nb) partial[tid] = buf[tid] - v;
}

__global__ void scan_finalize_kernel(const int* __restrict__ excl, const int* __restrict__ partial,
                                     int* __restrict__ row_start, int* __restrict__ cursor) {
    int i = blockIdx.x * blockDim.x + threadIdx.x;
    if (i < NN) {
        int v = excl[i] + partial[i >> 10];
        row_start[i] = v;
        cursor[i] = v;
    }
    if (i == NN) row_start[NN] = NE;
}

__global__ void bucket_kernel(const int* __restrict__ ei, int* __restrict__ cursor,
                              int* __restrict__ ssrc) {
    int e = blockIdx.x * blockDim.x + threadIdx.x;
    if (e < NE) {
        int s = ei[e];
        int d = ei[NE + e];
        int pos = atomicAdd(&cursor[d], 1);
        ssrc[pos] = s;
    }
}

// ---------------------------------------------------------------------------
// GEMM layer 1: out[M,128] = bf16( (A[M,128] @ W[128,128]) * dis[row] )
// BM=128, BK=32, 8x8 micro-tile: 64 FMA per 4 ds_read_b128.
// ---------------------------------------------------------------------------
__global__ __launch_bounds__(256) void gemm128_kernel(
        const float* __restrict__ A, const float* __restrict__ W,
        const float* __restrict__ dis, ushort16* __restrict__ out, int M) {
    constexpr int BM = 128, BK = 32, K = K_DIM, N = 128;
    constexpr int AP = BM + 4;        // 132: keeps 16B alignment of rows

    __shared__ float As[BK][AP];      // transposed: As[k][m], 16.9 KB
    __shared__ float Bs[BK][N];       // 16 KB

    int tid = threadIdx.x;
    int tx = tid % 16, ty = tid / 16;
    int row0 = blockIdx.x * BM;

    float acc[8][8] = {};

    for (int k0 = 0; k0 < K; k0 += BK) {
        {
            int r = tid >> 3;           // 0..31
            int c = (tid & 7) * 4;      // 0..28
            #pragma unroll
            for (int rr = 0; rr < BM; rr += 32) {
                int ra = row0 + r + rr;
                float4 v = (ra < M) ? *(const float4*)&A[(size_t)ra * K + k0 + c]
                                    : make_float4(0.f, 0.f, 0.f, 0.f);
                As[c + 0][r + rr] = v.x; As[c + 1][r + rr] = v.y;
                As[c + 2][r + rr] = v.z; As[c + 3][r + rr] = v.w;
            }
        }
        {
            int idx = tid * 4;
            #pragma unroll
            for (int base = 0; base < BK * N; base += 1024) {
                int ii = base + idx;
                int rB = ii >> 7, cB = ii & 127;
                *(float4*)&Bs[rB][cB] = *(const float4*)&W[(size_t)(k0 + rB) * N + cB];
            }
        }
        __syncthreads();
        #pragma unroll
        for (int kk = 0; kk < BK; kk++) {
            float a[8], b[8];
            *(float4*)&a[0] = *(const float4*)&As[kk][ty * 8];
            *(float4*)&a[4] = *(const float4*)&As[kk][ty * 8 + 4];
            *(float4*)&b[0] = *(const float4*)&Bs[kk][tx * 8];
            *(float4*)&b[4] = *(const float4*)&Bs[kk][tx * 8 + 4];
            #pragma unroll
            for (int i = 0; i < 8; i++)
                #pragma unroll
                for (int j = 0; j < 8; j++) acc[i][j] += a[i] * b[j];
        }
        __syncthreads();
    }

    #pragma unroll
    for (int i = 0; i < 8; i++) {
        int row = row0 + ty * 8 + i;
        if (row < M) {
            float s = dis[row];
            ushort4 v0, v1;
            v0.x = f2bf(acc[i][0] * s); v0.y = f2bf(acc[i][1] * s);
            v0.z = f2bf(acc[i][2] * s); v0.w = f2bf(acc[i][3] * s);
            v1.x = f2bf(acc[i][4] * s); v1.y = f2bf(acc[i][5] * s);
            v1.z = f2bf(acc[i][6] * s); v1.w = f2bf(acc[i][7] * s);
            *(ushort4*)&out[(size_t)row * N + tx * 8] = v0;
            *(ushort4*)&out[(size_t)row * N + tx * 8 + 4] = v1;
        }
    }
}

// ---------------------------------------------------------------------------
// GEMM layer 2 (N=64): out[M,64] = bf16( (A[M,128] @ W[128,64]) * dis[row] )
// BM=64, BK=32 (round-1 structure, known-correct).
// ---------------------------------------------------------------------------
__global__ __launch_bounds__(256) void gemm64_kernel(
        const float* __restrict__ A, const float* __restrict__ W,
        const float* __restrict__ dis, ushort16* __restrict__ out, int M) {
    constexpr int BM = 64, BK = 32, K = K_DIM, N = 64;
    constexpr int TN = 4, TX = 16, TY = 16, TM = 4;
    constexpr int AP = BM + 4;

    __shared__ float As[BK][AP];
    __shared__ float Bs[BK][N];

    int tid = threadIdx.x;
    int tx = tid % TX, ty = tid / TX;
    int row0 = blockIdx.x * BM;

    float acc[TM][TN] = {};

    for (int k0 = 0; k0 < K; k0 += BK) {
        {
            int r = tid >> 3;
            int c = (tid & 7) * 4;
            float4 z = make_float4(0.f, 0.f, 0.f, 0.f);
            int ra = row0 + r;
            float4 va = (ra < M) ? *(const float4*)&A[(size_t)ra * K + k0 + c] : z;
            int rb = row0 + r + 32;
            float4 vb = (rb < M) ? *(const float4*)&A[(size_t)rb * K + k0 + c] : z;
            As[c + 0][r] = va.x; As[c + 1][r] = va.y; As[c + 2][r] = va.z; As[c + 3][r] = va.w;
            As[c + 0][r + 32] = vb.x; As[c + 1][r + 32] = vb.y;
            As[c + 2][r + 32] = vb.z; As[c + 3][r + 32] = vb.w;
        }
        {
            constexpr int total = BK * N;   // 2048
            int idx = tid * 4;
            #pragma unroll
            for (int base = 0; base < total; base += 1024) {
                int ii = base + idx;
                if (ii < total) {
                    int rB = ii / N, cB = ii % N;
                    *(float4*)&Bs[rB][cB] = *(const float4*)&W[(size_t)(k0 + rB) * N + cB];
                }
            }
        }
        __syncthreads();
        #pragma unroll
        for (int kk = 0; kk < BK; kk++) {
            float a[TM], b[TN];
            *(float4*)&a[0] = *(const float4*)&As[kk][ty * TM];
            *(float4*)&b[0] = *(const float4*)&Bs[kk][tx * TN];
            #pragma unroll
            for (int i = 0; i < TM; i++)
                #pragma unroll
                for (int j = 0; j < TN; j++) acc[i][j] += a[i] * b[j];
        }
        __syncthreads();
    }

    #pragma unroll
    for (int i = 0; i < TM; i++) {
        int row = row0 + ty * TM + i;
        if (row < M) {
            float s = dis[row];
            ushort4 v;
            v.x = f2bf(acc[i][0] * s); v.y = f2bf(acc[i][1] * s);
            v.z = f2bf(acc[i][2] * s); v.w = f2bf(acc[i][3] * s);
            *(ushort4*)&out[(size_t)row * N + tx * TN] = v;
        }
    }
}

// ---------------------------------------------------------------------------
// Aggregation layer 1: F=128, bf16 gather -> f32 out with ReLU.
// One wave per node. Batches 8 edge indices per coalesced load, broadcasts
// via __shfl, issues 8 independent gathers (8x memory-level parallelism).
// ---------------------------------------------------------------------------
__global__ __launch_bounds__(256) void agg128_kernel(
        const ushort16* __restrict__ g, const int* __restrict__ row_start,
        const int* __restrict__ ssrc, const float* __restrict__ dis,
        const float* __restrict__ bias, float* __restrict__ out) {
    int wave = (blockIdx.x * 256 + threadIdx.x) >> 6;
    int lane = threadIdx.x & 63;
    if (wave >= NN) return;

    int beg = row_start[wave];
    int end = row_start[wave + 1];
    float sc = dis[wave];

    float ax = 0.f, ay = 0.f;
    int e = beg;
    for (; e + 8 <= end; e += 8) {
        int idx = ssrc[e + (lane & 7)];
        #pragma unroll
        for (int j = 0; j < 8; j++) {
            int s = __shfl(idx, j);
            uint32 u = *(const uint32*)&g[(size_t)s * 128 + lane * 2];
            ax += bf_lo(u);
            ay += bf_hi(u);
        }
    }
    if (e < end) {
        int n = end - e;                               // 1..7
        int idx = ssrc[min(e + (lane & 7), end - 1)];  // clamped: always valid
        #pragma unroll
        for (int j = 0; j < 8; j++) {
            int s = __shfl(idx, j);
            uint32 u = *(const uint32*)&g[(size_t)s * 128 + lane * 2];
            if (j < n) { ax += bf_lo(u); ay += bf_hi(u); }
        }
    }
    float2 b = *(const float2*)&bias[lane * 2];
    float ox = fmaxf(sc * ax + b.x, 0.f);
    float oy = fmaxf(sc * ay + b.y, 0.f);
    *(float2*)&out[(size_t)wave * 128 + lane * 2] = make_float2(ox, oy);
}

// ---------------------------------------------------------------------------
// Aggregation layer 2: F=64, bf16 gather -> f32 out (no activation).
// One wave per node; half-waves process alternating edges (4B/lane), 16-edge
// index batches -> 8 independent gathers per half-wave in flight.
// ---------------------------------------------------------------------------
__global__ __launch_bounds__(256) void agg64_kernel(
        const ushort16* __restrict__ g, const int* __restrict__ row_start,
        const int* __restrict__ ssrc, const float* __restrict__ dis,
        const float* __restrict__ bias, float* __restrict__ out) {
    int wave = (blockIdx.x * 256 + threadIdx.x) >> 6;
    int lane = threadIdx.x & 63;
    if (wave >= NN) return;

    int beg = row_start[wave];
    int end = row_start[wave + 1];
    float sc = dis[wave];
    int half = lane >> 5;       // which edge of each pair
    int l2 = lane & 31;         // feature pair index

    float ax = 0.f, ay = 0.f;
    int e = beg;
    for (; e + 16 <= end; e += 16) {
        int idx = ssrc[e + (lane & 15)];
        #pragma unroll
        for (int j = 0; j < 8; j++) {
            int s = __shfl(idx, j * 2 + half);
            uint32 u = *(const uint32*)&g[(size_t)s * 64 + l2 * 2];
            ax += bf_lo(u);
            ay += bf_hi(u);
        }
    }
    if (e < end) {
        int n = end - e;                                // 1..15
        int idx = ssrc[min(e + (lane & 15), end - 1)];  // clamped: always valid
        #pragma unroll
        for (int j = 0; j < 8; j++) {
            int jj = j * 2 + half;
            int s = __shfl(idx, jj);
            uint32 u = *(const uint32*)&g[(size_t)s * 64 + l2 * 2];
            if (jj < n) { ax += bf_lo(u); ay += bf_hi(u); }
        }
    }
    ax += __shfl_xor(ax, 32);
    ay += __shfl_xor(ay, 32);
    if (half == 0) {
        float2 b = *(const float2*)&bias[l2 * 2];
        *(float2*)&out[(size_t)wave * 64 + l2 * 2] =
            make_float2(sc * ax + b.x, sc * ay + b.y);
    }
}

// ---------------------------------------------------------------------------
// Launch
// ---------------------------------------------------------------------------
extern "C" void kernel_launch(void* const* d_in, const int* in_sizes, int n_in,
                              void* d_out, int out_size, void* d_ws, size_t ws_size,
                              hipStream_t stream) {
    const float* x  = (const float*)d_in[0];
    const int*   ei = (const int*)d_in[1];       // [2, NE] int32 per harness contract
    const float* W1 = (const float*)d_in[2];
    const float* b1 = (const float*)d_in[3];
    const float* W2 = (const float*)d_in[4];
    const float* b2 = (const float*)d_in[5];
    float* out = (float*)d_out;

    char* ws = (char*)d_ws;
    size_t off = 0;
    auto alloc = [&](size_t bytes) {
        void* p = ws + off;
        off = (off + bytes + 255) & ~(size_t)255;
        return p;
    };

    int*      deg_i     = (int*)alloc(NN * 4);
    float*    dis       = (float*)alloc(NN * 4);
    int*      excl      = (int*)alloc(NN * 4);
    int*      partials  = (int*)alloc(128 * 4);
    int*      row_start = (int*)alloc((NN + 1) * 4);
    int*      cursor    = (int*)alloc(NN * 4);
    int*      ssrc      = (int*)alloc((size_t)NE * 4);
    ushort16* g1        = (ushort16*)alloc((size_t)NN * 128 * 2);  // bf16, reused as g2
    float*    h         = (float*)alloc((size_t)NN * 128 * 4);     // f32 hidden
    ushort16* g2        = g1;  // alias: g1 dead after agg1

    hipMemsetAsync(deg_i, 0, NN * 4, stream);

    const int TB = 256;
    deg_count_kernel<<<(NE + TB - 1) / TB, TB, 0, stream>>>(ei, deg_i);
    dis_kernel<<<(NN + TB - 1) / TB, TB, 0, stream>>>(deg_i, dis);

    const int NB_SCAN = (NN + 1023) / 1024;   // 98
    scan_block_kernel<<<NB_SCAN, 1024, 0, stream>>>(deg_i, excl, partials);
    scan_partials_kernel<<<1, 128, 0, stream>>>(partials, NB_SCAN);
    scan_finalize_kernel<<<(NN + 1 + TB - 1) / TB, TB, 0, stream>>>(excl, partials, row_start, cursor);

    bucket_kernel<<<(NE + TB - 1) / TB, TB, 0, stream>>>(ei, cursor, ssrc);

    gemm128_kernel<<<(NN + 127) / 128, 256, 0, stream>>>(x, W1, dis, g1, NN);

    const int AGG_BLOCKS = (NN + 3) / 4;      // 25000 (4 waves/block)
    agg128_kernel<<<AGG_BLOCKS, 256, 0, stream>>>(g1, row_start, ssrc, dis, b1, h);

    gemm64_kernel<<<(NN + 63) / 64, 256, 0, stream>>>(h, W2, dis, g2, NN);

    agg64_kernel<<<AGG_BLOCKS, 256, 0, stream>>>(g2, row_start, ssrc, dis, b2, out);
}

// Round 4
// 425.201 us; speedup vs baseline: 1.6279x; 1.1429x over previous
//
#include <hip/hip_runtime.h>
#include <stdint.h>

// Problem constants (fixed by reference)
#define NN 100000      // nodes
#define NE 1600000     // edges
#define K_DIM 128      // IN_DIM == HID_DIM

// Coarse binning for CSR build
#define BSH 7                                   // 128 nodes per bucket
#define NBKT ((NN + (1 << BSH) - 1) >> BSH)     // 782 buckets
#define EPT 32                                  // edges per thread, pass 1
#define BIN_CHUNK (256 * EPT)                   // 8192 edges per block

typedef unsigned int uint32;
typedef unsigned short ushort16;

__device__ __forceinline__ ushort16 f2bf(float f) {
    uint32 u = __float_as_uint(f);
    u += 0x7fffu + ((u >> 16) & 1u);   // round-to-nearest-even
    return (ushort16)(u >> 16);
}
__device__ __forceinline__ float bf_lo(uint32 u) { return __uint_as_float(u << 16); }
__device__ __forceinline__ float bf_hi(uint32 u) { return __uint_as_float(u & 0xffff0000u); }

// ---------------------------------------------------------------------------
// CSR build: degree count -> exclusive scan -> two-pass binned scatter
// ---------------------------------------------------------------------------

__global__ void deg_count_kernel(const int* __restrict__ ei, int* __restrict__ deg) {
    int e = blockIdx.x * blockDim.x + threadIdx.x;
    if (e < NE) {
        int d = ei[NE + e];
        atomicAdd(&deg[d], 1);
    }
}

__global__ void dis_kernel(const int* __restrict__ deg, float* __restrict__ dis) {
    int i = blockIdx.x * blockDim.x + threadIdx.x;
    if (i < NN) {
        int d = deg[i];
        dis[i] = (d > 0) ? rsqrtf((float)d) : 0.0f;
    }
}

__global__ void scan_block_kernel(const int* __restrict__ deg, int* __restrict__ excl,
                                  int* __restrict__ partial) {
    __shared__ int buf[1024];
    int tid = threadIdx.x;
    int i = blockIdx.x * 1024 + tid;
    int v = (i < NN) ? deg[i] : 0;
    buf[tid] = v;
    __syncthreads();
    for (int off = 1; off < 1024; off <<= 1) {
        int t = (tid >= off) ? buf[tid - off] : 0;
        __syncthreads();
        buf[tid] += t;
        __syncthreads();
    }
    if (i < NN) excl[i] = buf[tid] - v;
    if (tid == 1023) partial[blockIdx.x] = buf[1023];
}

__global__ void scan_partials_kernel(int* __restrict__ partial, int nb) {
    __shared__ int buf[128];
    int tid = threadIdx.x;
    int v = (tid < nb) ? partial[tid] : 0;
    buf[tid] = v;
    __syncthreads();
    for (int off = 1; off < 128; off <<= 1) {
        int t = (tid >= off) ? buf[tid - off] : 0;
        __syncthreads();
        buf[tid] += t;
        __syncthreads();
    }
    if (tid < nb) partial[tid] = buf[tid] - v;
}

__global__ void scan_finalize_kernel(const int* __restrict__ excl, const int* __restrict__ partial,
                                     int* __restrict__ row_start) {
    int i = blockIdx.x * blockDim.x + threadIdx.x;
    if (i < NN) row_start[i] = excl[i] + partial[i >> 10];
    if (i == NN) row_start[NN] = NE;
}

// gcursor[b] = staging start of bucket b = row_start[b << BSH]
__global__ void bucket_base_kernel(const int* __restrict__ row_start, int* __restrict__ gcursor) {
    int b = blockIdx.x * blockDim.x + threadIdx.x;
    if (b < NBKT) {
        int node = b << BSH;
        gcursor[b] = row_start[node < NN ? node : NN];
    }
}

// Pass 1: bin (src,dst) pairs into 782 coarse buckets in staging.
// Per-block: LDS histogram -> per-bucket global reserve -> chunked scatter.
// Each (block,bucket) chunk is contiguous => L2 merges into full-line writebacks.
__global__ __launch_bounds__(256) void bin_pass1_kernel(
        const int* __restrict__ ei, int* __restrict__ gcursor,
        uint2* __restrict__ staging) {
    __shared__ int hist[NBKT];
    __shared__ int base[NBKT];
    int tid = threadIdx.x;
    int e0 = blockIdx.x * BIN_CHUNK;

    for (int i = tid; i < NBKT; i += 256) hist[i] = 0;
    __syncthreads();

    // phase A: per-block bucket histogram
    #pragma unroll
    for (int k = 0; k < EPT; k++) {
        int e = e0 + k * 256 + tid;
        if (e < NE) {
            int d = ei[NE + e];
            atomicAdd(&hist[d >> BSH], 1);
        }
    }
    __syncthreads();

    // phase B: reserve contiguous chunks in staging
    for (int i = tid; i < NBKT; i += 256) {
        int c = hist[i];
        base[i] = c ? atomicAdd(&gcursor[i], c) : 0;
        hist[i] = 0;
    }
    __syncthreads();

    // phase C: scatter pairs into reserved chunks
    #pragma unroll
    for (int k = 0; k < EPT; k++) {
        int e = e0 + k * 256 + tid;
        if (e < NE) {
            int s = ei[e];
            int d = ei[NE + e];
            int b = d >> BSH;
            int off = atomicAdd(&hist[b], 1);
            staging[(size_t)base[b] + off] = make_uint2((uint32)s, (uint32)d);
        }
    }
}

// Pass 2: one block per bucket; LDS per-dst cursors; fine scatter into ssrc.
// Write window per block = one contiguous CSR segment (~65 KB) => full locality.
__global__ __launch_bounds__(256) void bin_pass2_kernel(
        const uint2* __restrict__ staging, const int* __restrict__ row_start,
        int* __restrict__ ssrc) {
    __shared__ int cur[1 << BSH];
    int b = blockIdx.x;
    int node0 = b << BSH;
    int tid = threadIdx.x;

    if (tid < (1 << BSH)) {
        int node = node0 + tid;
        cur[tid] = (node < NN) ? row_start[node] : 0;
    }
    int beg = row_start[node0];
    int endn = node0 + (1 << BSH); if (endn > NN) endn = NN;
    int end = row_start[endn];
    __syncthreads();

    for (int i = beg + tid; i < end; i += 256) {
        uint2 p = staging[i];
        int off = atomicAdd(&cur[p.y - node0], 1);
        ssrc[off] = (int)p.x;
    }
}

// ---------------------------------------------------------------------------
// GEMM layer 1: out[M,128] = bf16( (A[M,128] @ W[128,128]) * dis[row] )
// BM=128, BK=32, 8x8 micro-tile: 64 FMA per 4 ds_read_b128.
// ---------------------------------------------------------------------------
__global__ __launch_bounds__(256) void gemm128_kernel(
        const float* __restrict__ A, const float* __restrict__ W,
        const float* __restrict__ dis, ushort16* __restrict__ out, int M) {
    constexpr int BM = 128, BK = 32, K = K_DIM, N = 128;
    constexpr int AP = BM + 4;

    __shared__ float As[BK][AP];
    __shared__ float Bs[BK][N];

    int tid = threadIdx.x;
    int tx = tid % 16, ty = tid / 16;
    int row0 = blockIdx.x * BM;

    float acc[8][8] = {};

    for (int k0 = 0; k0 < K; k0 += BK) {
        {
            int r = tid >> 3;
            int c = (tid & 7) * 4;
            #pragma unroll
            for (int rr = 0; rr < BM; rr += 32) {
                int ra = row0 + r + rr;
                float4 v = (ra < M) ? *(const float4*)&A[(size_t)ra * K + k0 + c]
                                    : make_float4(0.f, 0.f, 0.f, 0.f);
                As[c + 0][r + rr] = v.x; As[c + 1][r + rr] = v.y;
                As[c + 2][r + rr] = v.z; As[c + 3][r + rr] = v.w;
            }
        }
        {
            int idx = tid * 4;
            #pragma unroll
            for (int base = 0; base < BK * N; base += 1024) {
                int ii = base + idx;
                int rB = ii >> 7, cB = ii & 127;
                *(float4*)&Bs[rB][cB] = *(const float4*)&W[(size_t)(k0 + rB) * N + cB];
            }
        }
        __syncthreads();
        #pragma unroll
        for (int kk = 0; kk < BK; kk++) {
            float a[8], bv[8];
            *(float4*)&a[0] = *(const float4*)&As[kk][ty * 8];
            *(float4*)&a[4] = *(const float4*)&As[kk][ty * 8 + 4];
            *(float4*)&bv[0] = *(const float4*)&Bs[kk][tx * 8];
            *(float4*)&bv[4] = *(const float4*)&Bs[kk][tx * 8 + 4];
            #pragma unroll
            for (int i = 0; i < 8; i++)
                #pragma unroll
                for (int j = 0; j < 8; j++) acc[i][j] += a[i] * bv[j];
        }
        __syncthreads();
    }

    #pragma unroll
    for (int i = 0; i < 8; i++) {
        int row = row0 + ty * 8 + i;
        if (row < M) {
            float s = dis[row];
            ushort4 v0, v1;
            v0.x = f2bf(acc[i][0] * s); v0.y = f2bf(acc[i][1] * s);
            v0.z = f2bf(acc[i][2] * s); v0.w = f2bf(acc[i][3] * s);
            v1.x = f2bf(acc[i][4] * s); v1.y = f2bf(acc[i][5] * s);
            v1.z = f2bf(acc[i][6] * s); v1.w = f2bf(acc[i][7] * s);
            *(ushort4*)&out[(size_t)row * N + tx * 8] = v0;
            *(ushort4*)&out[(size_t)row * N + tx * 8 + 4] = v1;
        }
    }
}

// ---------------------------------------------------------------------------
// GEMM layer 2 (N=64): out[M,64] = bf16( (A[M,128] @ W[128,64]) * dis[row] )
// ---------------------------------------------------------------------------
__global__ __launch_bounds__(256) void gemm64_kernel(
        const float* __restrict__ A, const float* __restrict__ W,
        const float* __restrict__ dis, ushort16* __restrict__ out, int M) {
    constexpr int BM = 64, BK = 32, K = K_DIM, N = 64;
    constexpr int TN = 4, TX = 16, TM = 4;
    constexpr int AP = BM + 4;

    __shared__ float As[BK][AP];
    __shared__ float Bs[BK][N];

    int tid = threadIdx.x;
    int tx = tid % TX, ty = tid / TX;
    int row0 = blockIdx.x * BM;

    float acc[TM][TN] = {};

    for (int k0 = 0; k0 < K; k0 += BK) {
        {
            int r = tid >> 3;
            int c = (tid & 7) * 4;
            float4 z = make_float4(0.f, 0.f, 0.f, 0.f);
            int ra = row0 + r;
            float4 va = (ra < M) ? *(const float4*)&A[(size_t)ra * K + k0 + c] : z;
            int rb = row0 + r + 32;
            float4 vb = (rb < M) ? *(const float4*)&A[(size_t)rb * K + k0 + c] : z;
            As[c + 0][r] = va.x; As[c + 1][r] = va.y; As[c + 2][r] = va.z; As[c + 3][r] = va.w;
            As[c + 0][r + 32] = vb.x; As[c + 1][r + 32] = vb.y;
            As[c + 2][r + 32] = vb.z; As[c + 3][r + 32] = vb.w;
        }
        {
            constexpr int total = BK * N;
            int idx = tid * 4;
            #pragma unroll
            for (int base = 0; base < total; base += 1024) {
                int ii = base + idx;
                if (ii < total) {
                    int rB = ii / N, cB = ii % N;
                    *(float4*)&Bs[rB][cB] = *(const float4*)&W[(size_t)(k0 + rB) * N + cB];
                }
            }
        }
        __syncthreads();
        #pragma unroll
        for (int kk = 0; kk < BK; kk++) {
            float a[TM], bv[TN];
            *(float4*)&a[0] = *(const float4*)&As[kk][ty * TM];
            *(float4*)&bv[0] = *(const float4*)&Bs[kk][tx * TN];
            #pragma unroll
            for (int i = 0; i < TM; i++)
                #pragma unroll
                for (int j = 0; j < TN; j++) acc[i][j] += a[i] * bv[j];
        }
        __syncthreads();
    }

    #pragma unroll
    for (int i = 0; i < TM; i++) {
        int row = row0 + ty * TM + i;
        if (row < M) {
            float s = dis[row];
            ushort4 v;
            v.x = f2bf(acc[i][0] * s); v.y = f2bf(acc[i][1] * s);
            v.z = f2bf(acc[i][2] * s); v.w = f2bf(acc[i][3] * s);
            *(ushort4*)&out[(size_t)row * N + tx * TN] = v;
        }
    }
}

// ---------------------------------------------------------------------------
// Aggregation layer 1: F=128, bf16 gather -> f32 out with ReLU.
// One wave per node; 8-edge index batches -> 8 independent gathers in flight.
// ---------------------------------------------------------------------------
__global__ __launch_bounds__(256) void agg128_kernel(
        const ushort16* __restrict__ g, const int* __restrict__ row_start,
        const int* __restrict__ ssrc, const float* __restrict__ dis,
        const float* __restrict__ bias, float* __restrict__ out) {
    int wave = (blockIdx.x * 256 + threadIdx.x) >> 6;
    int lane = threadIdx.x & 63;
    if (wave >= NN) return;

    int beg = row_start[wave];
    int end = row_start[wave + 1];
    float sc = dis[wave];

    float ax = 0.f, ay = 0.f;
    int e = beg;
    for (; e + 8 <= end; e += 8) {
        int idx = ssrc[e + (lane & 7)];
        #pragma unroll
        for (int j = 0; j < 8; j++) {
            int s = __shfl(idx, j);
            uint32 u = *(const uint32*)&g[(size_t)s * 128 + lane * 2];
            ax += bf_lo(u);
            ay += bf_hi(u);
        }
    }
    if (e < end) {
        int n = end - e;
        int idx = ssrc[min(e + (lane & 7), end - 1)];
        #pragma unroll
        for (int j = 0; j < 8; j++) {
            int s = __shfl(idx, j);
            uint32 u = *(const uint32*)&g[(size_t)s * 128 + lane * 2];
            if (j < n) { ax += bf_lo(u); ay += bf_hi(u); }
        }
    }
    float2 b = *(const float2*)&bias[lane * 2];
    float ox = fmaxf(sc * ax + b.x, 0.f);
    float oy = fmaxf(sc * ay + b.y, 0.f);
    *(float2*)&out[(size_t)wave * 128 + lane * 2] = make_float2(ox, oy);
}

// ---------------------------------------------------------------------------
// Aggregation layer 2: F=64, bf16 gather -> f32 out (no activation).
// Half-waves process alternating edges; 16-edge batches.
// ---------------------------------------------------------------------------
__global__ __launch_bounds__(256) void agg64_kernel(
        const ushort16* __restrict__ g, const int* __restrict__ row_start,
        const int* __restrict__ ssrc, const float* __restrict__ dis,
        const float* __restrict__ bias, float* __restrict__ out) {
    int wave = (blockIdx.x * 256 + threadIdx.x) >> 6;
    int lane = threadIdx.x & 63;
    if (wave >= NN) return;

    int beg = row_start[wave];
    int end = row_start[wave + 1];
    float sc = dis[wave];
    int half = lane >> 5;
    int l2 = lane & 31;

    float ax = 0.f, ay = 0.f;
    int e = beg;
    for (; e + 16 <= end; e += 16) {
        int idx = ssrc[e + (lane & 15)];
        #pragma unroll
        for (int j = 0; j < 8; j++) {
            int s = __shfl(idx, j * 2 + half);
            uint32 u = *(const uint32*)&g[(size_t)s * 64 + l2 * 2];
            ax += bf_lo(u);
            ay += bf_hi(u);
        }
    }
    if (e < end) {
        int n = end - e;
        int idx = ssrc[min(e + (lane & 15), end - 1)];
        #pragma unroll
        for (int j = 0; j < 8; j++) {
            int jj = j * 2 + half;
            int s = __shfl(idx, jj);
            uint32 u = *(const uint32*)&g[(size_t)s * 64 + l2 * 2];
            if (jj < n) { ax += bf_lo(u); ay += bf_hi(u); }
        }
    }
    ax += __shfl_xor(ax, 32);
    ay += __shfl_xor(ay, 32);
    if (half == 0) {
        float2 b = *(const float2*)&bias[l2 * 2];
        *(float2*)&out[(size_t)wave * 64 + l2 * 2] =
            make_float2(sc * ax + b.x, sc * ay + b.y);
    }
}

// ---------------------------------------------------------------------------
// Launch
// ---------------------------------------------------------------------------
extern "C" void kernel_launch(void* const* d_in, const int* in_sizes, int n_in,
                              void* d_out, int out_size, void* d_ws, size_t ws_size,
                              hipStream_t stream) {
    const float* x  = (const float*)d_in[0];
    const int*   ei = (const int*)d_in[1];
    const float* W1 = (const float*)d_in[2];
    const float* b1 = (const float*)d_in[3];
    const float* W2 = (const float*)d_in[4];
    const float* b2 = (const float*)d_in[5];
    float* out = (float*)d_out;

    char* ws = (char*)d_ws;
    size_t off = 0;
    auto alloc = [&](size_t bytes) {
        void* p = ws + off;
        off = (off + bytes + 255) & ~(size_t)255;
        return p;
    };

    int*      deg_i     = (int*)alloc(NN * 4);
    float*    dis       = (float*)alloc(NN * 4);
    int*      excl      = (int*)alloc(NN * 4);
    int*      partials  = (int*)alloc(128 * 4);
    int*      row_start = (int*)alloc((NN + 1) * 4);
    int*      gcursor   = (int*)alloc(NBKT * 4);
    int*      ssrc      = (int*)alloc((size_t)NE * 4);
    ushort16* g1        = (ushort16*)alloc((size_t)NN * 128 * 2);  // bf16, reused as g2
    float*    h         = (float*)alloc((size_t)NN * 128 * 4);     // f32 hidden
    ushort16* g2        = g1;                 // alias: g1 dead after agg1
    uint2*    staging   = (uint2*)h;          // alias: dead before h is written (12.8MB < 51.2MB)

    hipMemsetAsync(deg_i, 0, NN * 4, stream);

    const int TB = 256;
    deg_count_kernel<<<(NE + TB - 1) / TB, TB, 0, stream>>>(ei, deg_i);
    dis_kernel<<<(NN + TB - 1) / TB, TB, 0, stream>>>(deg_i, dis);

    const int NB_SCAN = (NN + 1023) / 1024;   // 98
    scan_block_kernel<<<NB_SCAN, 1024, 0, stream>>>(deg_i, excl, partials);
    scan_partials_kernel<<<1, 128, 0, stream>>>(partials, NB_SCAN);
    scan_finalize_kernel<<<(NN + 1 + TB - 1) / TB, TB, 0, stream>>>(excl, partials, row_start);
    bucket_base_kernel<<<(NBKT + TB - 1) / TB, TB, 0, stream>>>(row_start, gcursor);

    bin_pass1_kernel<<<(NE + BIN_CHUNK - 1) / BIN_CHUNK, 256, 0, stream>>>(ei, gcursor, staging);
    bin_pass2_kernel<<<NBKT, 256, 0, stream>>>(staging, row_start, ssrc);

    gemm128_kernel<<<(NN + 127) / 128, 256, 0, stream>>>(x, W1, dis, g1, NN);

    const int AGG_BLOCKS = (NN + 3) / 4;      // 25000 (4 waves/block)
    agg128_kernel<<<AGG_BLOCKS, 256, 0, stream>>>(g1, row_start, ssrc, dis, b1, h);

    gemm64_kernel<<<(NN + 63) / 64, 256, 0, stream>>>(h, W2, dis, g2, NN);

    agg64_kernel<<<AGG_BLOCKS, 256, 0, stream>>>(g2, row_start, ssrc, dis, b2, out);
}